// Round 3
// baseline (360.200 us; speedup 1.0000x reference)
//
#include <hip/hip_runtime.h>

#define DD 256
#define BB 512

// workspace layout (float offsets)
#define OFF_RS   0          // 512*256 row sums
#define OFF_CSP  131072     // 2048*256 col-sum partials (4 per batch)
#define OFF_HFC  655360     // 4 fc1 pre-activations
#define OFF_SBP  655368     // 10 sorted breakpoints
#define OFF_TAB  655384     // 11*18 packed (A,B) interval table

__device__ __forceinline__ float wave_red(float v) {
#pragma unroll
  for (int off = 32; off > 0; off >>= 1) v += __shfl_down(v, off, 64);
  return v;
}

// ---- build piecewise-linear tables: q_t(e) = A[s][t]*e + B[s][t], packed (A,B) ----
__global__ void ktab_kernel(const float* __restrict__ w1, const float* __restrict__ b1,
                            const float* __restrict__ w2, float* __restrict__ ws) {
  __shared__ float w2s[90];
  int tid = threadIdx.x;
  for (int t = tid; t < 90; t += 64) w2s[t] = w2[t];
  __syncthreads();
  float w1v[10], b1v[10], bp[10];
  int rank[10];
#pragma unroll
  for (int c = 0; c < 10; ++c) { w1v[c] = w1[c]; b1v[c] = b1[c]; bp[c] = -b1v[c] / w1v[c]; }
#pragma unroll
  for (int c = 0; c < 10; ++c) {
    int r = 0;
#pragma unroll
    for (int k = 0; k < 10; ++k)
      r += (bp[k] < bp[c] || (bp[k] == bp[c] && k < c)) ? 1 : 0;
    rank[c] = r;
  }
  if (tid < 10) ws[OFF_SBP + rank[tid]] = bp[tid];
  if (tid < 11) {
    int s = tid;  // interval: #breakpoints < e
    for (int t = 0; t < 9; ++t) {
      float A = 0.f, Bv = 0.f;
      for (int c = 0; c < 10; ++c) {
        bool act = (w1v[c] > 0.f) ? (rank[c] < s)
                 : ((w1v[c] < 0.f) ? (rank[c] >= s) : (b1v[c] > 0.f));
        if (act) { A += w1v[c] * w2s[c * 9 + t]; Bv += b1v[c] * w2s[c * 9 + t]; }
      }
      ws[OFF_TAB + s * 18 + t * 2]     = A;
      ws[OFF_TAB + s * 18 + t * 2 + 1] = Bv;
    }
  }
}

// ---- K1: row sums + col-sum partials; LDS-transpose row reduce ----
__global__ __launch_bounds__(256) void sum_kernel(const float* __restrict__ x,
                                                  float* __restrict__ ws) {
  const int bq = blockIdx.x;         // 2048 blocks: 4 per batch (64 rows each)
  const int b = bq >> 2;
  const int q = bq & 3;
  const int tid = threadIdx.x;
  const int lane = tid & 63;
  const int wv = tid >> 6;
  __shared__ float rowp[64][65];
  __shared__ float csl[4][DD];
  __shared__ float segp[4][64];
  float4 cacc = make_float4(0.f, 0.f, 0.f, 0.f);
  const float4* px = (const float4*)(x + ((size_t)b << 16) + ((size_t)(q * 64 + wv * 16) << 8));
#pragma unroll
  for (int r = 0; r < 16; ++r) {
    float4 val = px[r * 64 + lane];
    cacc.x += val.x; cacc.y += val.y; cacc.z += val.z; cacc.w += val.w;
    rowp[wv * 16 + r][lane] = (val.x + val.y) + (val.z + val.w);
  }
  ((float4*)csl[wv])[lane] = cacc;
  __syncthreads();
  {
    const int row = tid & 63, seg = tid >> 6;
    const float* rp = rowp[row] + seg * 16;
    float s = 0.f;
#pragma unroll
    for (int k = 0; k < 16; ++k) s += rp[k];
    segp[seg][row] = s;
  }
  __syncthreads();
  if (tid < 64)
    ws[OFF_RS + b * DD + q * 64 + tid] =
        (segp[0][tid] + segp[1][tid]) + (segp[2][tid] + segp[3][tid]);
  ws[OFF_CSP + bq * DD + tid] =
      (csl[0][tid] + csl[1][tid]) + (csl[2][tid] + csl[3][tid]);
  if (bq == 0 && tid < 4) ws[OFF_HFC + tid] = 0.f;
}

// ---- K2: fused conv+relu + direct fc1 accumulation, wave-level trivial-row skip ----
// Rows ir < jmin-2 give y = relu(b2) for every lane of the wave -> closed form.
__global__ __launch_bounds__(256) void conv_kernel(const float* __restrict__ b2p,
                                                   const float* __restrict__ fc1w,
                                                   float* __restrict__ ws) {
  const int blk = blockIdx.x;        // 4096 blocks: 8 chunks of 32 rows per image
  const int b = blk >> 3;
  const int chunk = blk & 7;
  const int r0 = chunk * 32, r1 = r0 + 32;
  const int tid = threadIdx.x;
  const int lane = tid & 63;
  const int wv = tid >> 6;
  const int j = tid;
  const int jmin = wv * 64;

  __shared__ float rs_s[DD];
  __shared__ float cs_s[DD];
  __shared__ float tab_s[198];
  __shared__ float sbp_s[10];
  __shared__ float wk_s[32][4];      // Wk[b, r0..r1-1]
  __shared__ float pwk_s[4][33];     // prefix sums of wk
  __shared__ float red_s[16];

  rs_s[tid] = ws[OFF_RS + b * DD + tid];
  const float* csp = ws + OFF_CSP + (b * 4) * DD + tid;
  cs_s[tid] = (csp[0] + csp[DD]) + (csp[2 * DD] + csp[3 * DD]);
  if (tid < 198) tab_s[tid] = ws[OFF_TAB + tid];
  if (tid >= 198 && tid < 208) sbp_s[tid - 198] = ws[OFF_SBP + tid - 198];
  if (tid >= 224) {
    const int r = tid - 224;         // 32 threads load wk rows
#pragma unroll
    for (int k = 0; k < 4; ++k) wk_s[r][k] = fc1w[k * (BB * DD) + b * DD + r0 + r];
  }
  __syncthreads();
  if (tid < 4) {                     // prefix sums (regs, independent LDS reads)
    float run = 0.f;
#pragma unroll
    for (int r = 0; r < 32; ++r) {
      pwk_s[tid][r] = run;
      run += wk_s[r][tid];
    }
    pwk_s[tid][32] = run;
  }

  float sbpv[10];
#pragma unroll
  for (int k = 0; k < 10; ++k) sbpv[k] = sbp_s[k];
  const float lo = sbpv[0], hi = sbpv[9];
  const float b2v = b2p[0];
  const float yb = fmaxf(b2v, 0.f);

  float A0r[9], B0r[9], A1r[9], B1r[9];
#pragma unroll
  for (int t = 0; t < 9; ++t) {
    A0r[t] = tab_s[t * 2];       B0r[t] = tab_s[t * 2 + 1];
    A1r[t] = tab_s[180 + t * 2]; B1r[t] = tab_s[180 + t * 2 + 1];
  }

  float csr[3], vf[3];
  csr[0] = (j >= 1) ? cs_s[j - 1] : 0.f;
  csr[1] = cs_s[j];
  csr[2] = (j < DD - 1) ? cs_s[j + 1] : 0.f;
  vf[0] = (j >= 1) ? 1.f : 0.f;
  vf[1] = 1.f;
  vf[2] = (j < DD - 1) ? 1.f : 0.f;

  const int ntv = min(max(jmin - 2 - r0, 0), 32);  // trivial rows for this wave
  const int ir0 = r0 + ntv;
  const int ifin = ir0 + 1;
  const int istart = (r0 == 0) ? 0 : r0 - 1;
  const int i_lo = (ntv > 0) ? ir0 - 1 : istart;
  const int iend = (r1 == DD) ? DD - 1 : r1;

  __syncthreads();                   // pwk ready

  float P = 0.f, Q = 0.f;
  float vcol = ntv * yb;             // closed-form trivial rows
  float acc0 = yb * pwk_s[0][ntv];
  float acc1 = yb * pwk_s[1][ntv];
  float acc2 = yb * pwk_s[2][ntv];
  float acc3 = yb * pwk_s[3][ntv];

  if (ntv < 32) {
    for (int i = i_lo; i <= iend; ++i) {
      const float rsv = rs_s[i];
      float R0 = 0.f, R1 = 0.f, R2 = 0.f;
      if (j - 1 <= i) {              // any tap unmasked for this lane
#pragma unroll
        for (int kc = 0; kc < 3; ++kc) {
          float e = rsv + csr[kc];
          bool pos = e > hi;
          float a0 = pos ? A1r[kc]     : A0r[kc];
          float a1 = pos ? A1r[3 + kc] : A0r[3 + kc];
          float a2 = pos ? A1r[6 + kc] : A0r[6 + kc];
          float g0 = pos ? B1r[kc]     : B0r[kc];
          float g1 = pos ? B1r[3 + kc] : B0r[3 + kc];
          float g2 = pos ? B1r[6 + kc] : B0r[6 + kc];
          if (e >= lo && e <= hi) {  // middle zone: exact interval, packed b64 reads
            int s = 0;
#pragma unroll
            for (int k = 0; k < 10; ++k) s += (sbpv[k] < e) ? 1 : 0;
            const float* tp = tab_s + s * 18 + kc * 2;
            float2 ab0 = *(const float2*)(tp);
            float2 ab1 = *(const float2*)(tp + 6);
            float2 ab2 = *(const float2*)(tp + 12);
            a0 = ab0.x; g0 = ab0.y;
            a1 = ab1.x; g1 = ab1.y;
            a2 = ab2.x; g2 = ab2.y;
          }
          float m = ((j - 1 + kc) <= i) ? vf[kc] : 0.f;  // tril + horiz edges
          R0 = fmaf(m, fmaf(a0, e, g0), R0);
          R1 = fmaf(m, fmaf(a1, e, g1), R1);
          R2 = fmaf(m, fmaf(a2, e, g2), R2);
        }
      }
      if (i >= ifin) {               // finalize output row i-1
        float y = fmaxf(P + R2 + b2v, 0.f);
        vcol += y;
        const float4 wkv = *(const float4*)wk_s[i - 1 - r0];
        acc0 = fmaf(y, wkv.x, acc0);
        acc1 = fmaf(y, wkv.y, acc1);
        acc2 = fmaf(y, wkv.z, acc2);
        acc3 = fmaf(y, wkv.w, acc3);
      }
      P = Q + R1;
      Q = R0;
    }
  }
  if (r1 == DD) {                    // flush output row 255
    float y = fmaxf(P + b2v, 0.f);
    vcol += y;
    const float4 wkv = *(const float4*)wk_s[31];
    acc0 = fmaf(y, wkv.x, acc0);
    acc1 = fmaf(y, wkv.y, acc1);
    acc2 = fmaf(y, wkv.z, acc2);
    acc3 = fmaf(y, wkv.w, acc3);
  }

  // column-sum term: vcol * Wk[b, j]
  const int nidx = b * DD + j;
  acc0 = fmaf(vcol, fc1w[0 * (BB * DD) + nidx], acc0);
  acc1 = fmaf(vcol, fc1w[1 * (BB * DD) + nidx], acc1);
  acc2 = fmaf(vcol, fc1w[2 * (BB * DD) + nidx], acc2);
  acc3 = fmaf(vcol, fc1w[3 * (BB * DD) + nidx], acc3);

  acc0 = wave_red(acc0); acc1 = wave_red(acc1);
  acc2 = wave_red(acc2); acc3 = wave_red(acc3);
  if (lane == 0) {
    red_s[wv * 4 + 0] = acc0; red_s[wv * 4 + 1] = acc1;
    red_s[wv * 4 + 2] = acc2; red_s[wv * 4 + 3] = acc3;
  }
  __syncthreads();
  if (tid < 4) {
    float s = (red_s[tid] + red_s[4 + tid]) + (red_s[8 + tid] + red_s[12 + tid]);
    atomicAdd(&ws[OFF_HFC + tid], s);
  }
}

// ---- K3: relu(fc1) -> fc2 -> 2 outputs ----
__global__ void fc_kernel(const float* __restrict__ fc1b, const float* __restrict__ fc2w,
                          const float* __restrict__ fc2b, const float* __restrict__ ws,
                          float* __restrict__ out) {
  if (threadIdx.x == 0 && blockIdx.x == 0) {
    float o0 = fc2b[0], o1 = fc2b[1];
#pragma unroll
    for (int k = 0; k < 4; ++k) {
      float h = fmaxf(ws[OFF_HFC + k] + fc1b[k], 0.f);
      o0 += fc2w[k] * h;
      o1 += fc2w[4 + k] * h;
    }
    out[0] = o0; out[1] = o1;
  }
}

extern "C" void kernel_launch(void* const* d_in, const int* in_sizes, int n_in,
                              void* d_out, int out_size, void* d_ws, size_t ws_size,
                              hipStream_t stream) {
  const float* x    = (const float*)d_in[0];
  const float* w1   = (const float*)d_in[1];
  const float* b1   = (const float*)d_in[2];
  const float* w2   = (const float*)d_in[3];
  const float* b2   = (const float*)d_in[4];
  const float* fc1w = (const float*)d_in[5];
  const float* fc1b = (const float*)d_in[6];
  const float* fc2w = (const float*)d_in[7];
  const float* fc2b = (const float*)d_in[8];
  float* out = (float*)d_out;
  float* ws  = (float*)d_ws;

  hipLaunchKernelGGL(ktab_kernel, dim3(1), dim3(64), 0, stream, w1, b1, w2, ws);
  hipLaunchKernelGGL(sum_kernel,  dim3(2048), dim3(256), 0, stream, x, ws);
  hipLaunchKernelGGL(conv_kernel, dim3(4096), dim3(256), 0, stream, b2, fc1w, ws);
  hipLaunchKernelGGL(fc_kernel,   dim3(1), dim3(64), 0, stream, fc1b, fc2w, fc2b, ws, out);
}

// Round 4
// 292.923 us; speedup vs baseline: 1.2297x; 1.2297x over previous
//
#include <hip/hip_runtime.h>

#define DD 256
#define BB 512

// workspace layout (float offsets)
#define OFF_RS   0          // 512*256 row sums
#define OFF_CSP  131072     // 2048*256 col-sum partials (4 per batch)
#define OFF_HFC  655360     // 4 fc1 pre-activations
#define OFF_SBP  655368     // 10 sorted breakpoints
#define OFF_TABP 655384     // 33*8 padded table: [(s*3+kc)*8 + dr*2] = A, +1 = B

__device__ __forceinline__ float wave_red(float v) {
#pragma unroll
  for (int off = 32; off > 0; off >>= 1) v += __shfl_down(v, off, 64);
  return v;
}

// ---- build PWL tables, parallel: thread t<99 -> (s, tap) cell ----
__global__ void ktab_kernel(const float* __restrict__ w1, const float* __restrict__ b1,
                            const float* __restrict__ w2, float* __restrict__ ws) {
  const int t = threadIdx.x;  // 128 threads
  float w1v[10], b1v[10], bp[10];
  int rank[10];
#pragma unroll
  for (int c = 0; c < 10; ++c) { w1v[c] = w1[c]; b1v[c] = b1[c]; bp[c] = -b1v[c] / w1v[c]; }
#pragma unroll
  for (int c = 0; c < 10; ++c) {
    int r = 0;
#pragma unroll
    for (int k = 0; k < 10; ++k)
      r += (bp[k] < bp[c] || (bp[k] == bp[c] && k < c)) ? 1 : 0;
    rank[c] = r;
  }
  if (t < 10) ws[OFF_SBP + rank[t]] = bp[t];
  if (t < 99) {
    const int s = t / 9, tt = t % 9;      // tt = dr*3 + kc
    const int dr = tt / 3, kc = tt % 3;
    float A = 0.f, Bv = 0.f;
    for (int c = 0; c < 10; ++c) {
      bool act = (w1v[c] > 0.f) ? (rank[c] < s)
               : ((w1v[c] < 0.f) ? (rank[c] >= s) : (b1v[c] > 0.f));
      if (act) { A += w1v[c] * w2[c * 9 + tt]; Bv += b1v[c] * w2[c * 9 + tt]; }
    }
    ws[OFF_TABP + (s * 3 + kc) * 8 + dr * 2]     = A;
    ws[OFF_TABP + (s * 3 + kc) * 8 + dr * 2 + 1] = Bv;
  }
}

// ---- K1: row sums + col-sum partials; LDS-transpose row reduce ----
__global__ __launch_bounds__(256) void sum_kernel(const float* __restrict__ x,
                                                  float* __restrict__ ws) {
  const int bq = blockIdx.x;         // 2048 blocks: 4 per batch (64 rows each)
  const int b = bq >> 2;
  const int q = bq & 3;
  const int tid = threadIdx.x;
  const int lane = tid & 63;
  const int wv = tid >> 6;
  __shared__ float rowp[64][65];
  __shared__ float csl[4][DD];
  __shared__ float segp[4][64];
  float4 cacc = make_float4(0.f, 0.f, 0.f, 0.f);
  const float4* px = (const float4*)(x + ((size_t)b << 16) + ((size_t)(q * 64 + wv * 16) << 8));
#pragma unroll
  for (int r = 0; r < 16; ++r) {
    float4 val = px[r * 64 + lane];
    cacc.x += val.x; cacc.y += val.y; cacc.z += val.z; cacc.w += val.w;
    rowp[wv * 16 + r][lane] = (val.x + val.y) + (val.z + val.w);
  }
  ((float4*)csl[wv])[lane] = cacc;
  __syncthreads();
  {
    const int row = tid & 63, seg = tid >> 6;
    const float* rp = rowp[row] + seg * 16;
    float s = 0.f;
#pragma unroll
    for (int k = 0; k < 16; ++k) s += rp[k];
    segp[seg][row] = s;
  }
  __syncthreads();
  if (tid < 64)
    ws[OFF_RS + b * DD + q * 64 + tid] =
        (segp[0][tid] + segp[1][tid]) + (segp[2][tid] + segp[3][tid]);
  ws[OFF_CSP + bq * DD + tid] =
      (csl[0][tid] + csl[1][tid]) + (csl[2][tid] + csl[3][tid]);
  if (bq == 0 && tid < 4) ws[OFF_HFC + tid] = 0.f;
}

// ---- K2: one block per image, 16 waves = 4 col-bands x 4 row-segments ----
// Branchless always-table inner loop; hfc accumulated directly.
__global__ __launch_bounds__(1024, 8) void conv_kernel(const float* __restrict__ b2p,
                                                       const float* __restrict__ fc1w,
                                                       float* __restrict__ ws) {
  const int b = blockIdx.x;          // 512 blocks
  const int tid = threadIdx.x;
  const int w = tid >> 6;            // wave 0..15
  const int lane = tid & 63;
  const int wb = w & 3;              // column band
  const int seg = w >> 2;            // row segment
  const int j = wb * 64 + lane;
  const int r0 = seg * 64;

  __shared__ __align__(16) float tabP[264];   // 33 rows * 8 floats
  __shared__ float rs_s[DD];
  __shared__ float cs_s[DD];
  __shared__ float wkT[4][DD];       // SoA: conflict-free for both [k][i] and [k][j]
  __shared__ float sbp_s[10];
  __shared__ float red_s[64];        // 16 waves * 4

  // ---- preamble, spread over 1024 threads ----
  if (tid < 256) {
    rs_s[tid] = ws[OFF_RS + b * DD + tid];
  } else if (tid < 512) {
    const int t = tid - 256;
    const float* csp = ws + OFF_CSP + (b * 4) * DD + t;
    cs_s[t] = (csp[0] + csp[DD]) + (csp[2 * DD] + csp[3 * DD]);
  } else if (tid < 768) {
    const int r = tid - 512;
#pragma unroll
    for (int k = 0; k < 4; ++k) wkT[k][r] = fc1w[k * (BB * DD) + b * DD + r];
  } else {
    const int u = tid - 768;
    if (u < 264) tabP[u] = ws[OFF_TABP + u];
    if (u >= 256) { /* covered above: u<264 only needs 264 threads */ }
    if (u < 10) sbp_s[u] = ws[OFF_SBP + u];  // (re-read ok, broadcast)
  }
  // tabP needs 264 but only 256 threads in last group: patch the tail
  if (tid < 8) tabP[256 + tid] = ws[OFF_TABP + 256 + tid];
  __syncthreads();

  float sbpv[10];
#pragma unroll
  for (int k = 0; k < 10; ++k) sbpv[k] = sbp_s[k];
  const float b2v = b2p[0];

  float csr[3], vf[3];
  csr[0] = (j >= 1) ? cs_s[j - 1] : 0.f;
  csr[1] = cs_s[j];
  csr[2] = (j < DD - 1) ? cs_s[j + 1] : 0.f;
  vf[0] = (j >= 1) ? 1.f : 0.f;
  vf[1] = 1.f;
  vf[2] = (j < DD - 1) ? 1.f : 0.f;

  const int istart = (r0 == 0) ? 0 : r0 - 1;  // 1 warmup row
  const int iend = (r0 + 64 == DD) ? DD - 1 : r0 + 64;
  const int ifin = r0 + 1;                    // first i that finalizes a row

  float P = 0.f, Q = 0.f, vcol = 0.f;
  float acc0 = 0.f, acc1 = 0.f, acc2 = 0.f, acc3 = 0.f;

  for (int i = istart; i <= iend; ++i) {
    const float rsv = rs_s[i];
    float R0 = 0.f, R1 = 0.f, R2 = 0.f;
    if (j - 1 <= i) {                // execz-skips trivial rows for the wave
#pragma unroll
      for (int kc = 0; kc < 3; ++kc) {
        const float e = rsv + csr[kc];
        int s = 0;
#pragma unroll
        for (int k = 0; k < 10; ++k) s += (sbpv[k] < e) ? 1 : 0;
        const float* tp = tabP + (s * 3 + kc) * 8;
        const float4 ab01 = *(const float4*)tp;        // A0,B0,A1,B1
        const float2 ab2  = *(const float2*)(tp + 4);  // A2,B2
        const float m = ((j - 1 + kc) <= i) ? vf[kc] : 0.f;
        R0 = fmaf(m, fmaf(ab01.x, e, ab01.y), R0);
        R1 = fmaf(m, fmaf(ab01.z, e, ab01.w), R1);
        R2 = fmaf(m, fmaf(ab2.x, e, ab2.y), R2);
      }
    }
    if (i >= ifin) {                 // finalize output row i-1
      const float y = fmaxf(P + R2 + b2v, 0.f);
      vcol += y;
      const int r = i - 1;
      acc0 = fmaf(y, wkT[0][r], acc0);
      acc1 = fmaf(y, wkT[1][r], acc1);
      acc2 = fmaf(y, wkT[2][r], acc2);
      acc3 = fmaf(y, wkT[3][r], acc3);
    }
    P = Q + R1;
    Q = R0;
  }
  if (r0 + 64 == DD) {               // flush output row 255
    const float y = fmaxf(P + b2v, 0.f);
    vcol += y;
    acc0 = fmaf(y, wkT[0][DD - 1], acc0);
    acc1 = fmaf(y, wkT[1][DD - 1], acc1);
    acc2 = fmaf(y, wkT[2][DD - 1], acc2);
    acc3 = fmaf(y, wkT[3][DD - 1], acc3);
  }

  // column-sum term: vcol * Wk[b, j] (weights already staged in LDS)
  acc0 = fmaf(vcol, wkT[0][j], acc0);
  acc1 = fmaf(vcol, wkT[1][j], acc1);
  acc2 = fmaf(vcol, wkT[2][j], acc2);
  acc3 = fmaf(vcol, wkT[3][j], acc3);

  acc0 = wave_red(acc0); acc1 = wave_red(acc1);
  acc2 = wave_red(acc2); acc3 = wave_red(acc3);
  if (lane == 0) {
    red_s[w * 4 + 0] = acc0; red_s[w * 4 + 1] = acc1;
    red_s[w * 4 + 2] = acc2; red_s[w * 4 + 3] = acc3;
  }
  __syncthreads();
  if (tid < 4) {
    float s = 0.f;
#pragma unroll
    for (int wv = 0; wv < 16; ++wv) s += red_s[wv * 4 + tid];
    atomicAdd(&ws[OFF_HFC + tid], s);
  }
}

// ---- K3: relu(fc1) -> fc2 -> 2 outputs ----
__global__ void fc_kernel(const float* __restrict__ fc1b, const float* __restrict__ fc2w,
                          const float* __restrict__ fc2b, const float* __restrict__ ws,
                          float* __restrict__ out) {
  if (threadIdx.x == 0 && blockIdx.x == 0) {
    float o0 = fc2b[0], o1 = fc2b[1];
#pragma unroll
    for (int k = 0; k < 4; ++k) {
      float h = fmaxf(ws[OFF_HFC + k] + fc1b[k], 0.f);
      o0 += fc2w[k] * h;
      o1 += fc2w[4 + k] * h;
    }
    out[0] = o0; out[1] = o1;
  }
}

extern "C" void kernel_launch(void* const* d_in, const int* in_sizes, int n_in,
                              void* d_out, int out_size, void* d_ws, size_t ws_size,
                              hipStream_t stream) {
  const float* x    = (const float*)d_in[0];
  const float* w1   = (const float*)d_in[1];
  const float* b1   = (const float*)d_in[2];
  const float* w2   = (const float*)d_in[3];
  const float* b2   = (const float*)d_in[4];
  const float* fc1w = (const float*)d_in[5];
  const float* fc1b = (const float*)d_in[6];
  const float* fc2w = (const float*)d_in[7];
  const float* fc2b = (const float*)d_in[8];
  float* out = (float*)d_out;
  float* ws  = (float*)d_ws;

  hipLaunchKernelGGL(ktab_kernel, dim3(1), dim3(128), 0, stream, w1, b1, w2, ws);
  hipLaunchKernelGGL(sum_kernel,  dim3(2048), dim3(256), 0, stream, x, ws);
  hipLaunchKernelGGL(conv_kernel, dim3(512), dim3(1024), 0, stream, b2, fc1w, ws);
  hipLaunchKernelGGL(fc_kernel,   dim3(1), dim3(64), 0, stream, fc1b, fc2w, fc2b, ws, out);
}

// Round 5
// 249.696 us; speedup vs baseline: 1.4426x; 1.1731x over previous
//
#include <hip/hip_runtime.h>

#define DD 256
#define BB 512
#define NL 2048            // e-quantization LUT entries

// workspace layout (float offsets)
#define OFF_RS   0          // 512*256 row sums
#define OFF_CSP  131072     // 2048*256 col-sum partials (4 per batch)
#define OFF_HFC  655360     // 4 fc1 pre-activations
#define OFF_PAR  655368     // inv_step, bias
#define OFF_TABP 655376     // 33*8 padded table: byte off = s*96 + kc*32 (+16 for dr2)
#define OFF_LUT  655648     // 2048 u16: quantized e -> s*96 byte offset

__device__ __forceinline__ float wave_red(float v) {
#pragma unroll
  for (int off = 32; off > 0; off >>= 1) v += __shfl_down(v, off, 64);
  return v;
}

// ---- build PWL coefficient table + quantized interval LUT ----
__global__ void ktab_kernel(const float* __restrict__ w1, const float* __restrict__ b1,
                            const float* __restrict__ w2, float* __restrict__ ws) {
  const int t = threadIdx.x;  // 256 threads
  float w1v[10], b1v[10], bp[10];
  int rank[10];
#pragma unroll
  for (int c = 0; c < 10; ++c) { w1v[c] = w1[c]; b1v[c] = b1[c]; bp[c] = -b1v[c] / w1v[c]; }
#pragma unroll
  for (int c = 0; c < 10; ++c) {
    int r = 0;
#pragma unroll
    for (int k = 0; k < 10; ++k)
      r += (bp[k] < bp[c] || (bp[k] == bp[c] && k < c)) ? 1 : 0;
    rank[c] = r;
  }
  float lo = bp[0], hi = bp[0];
#pragma unroll
  for (int c = 1; c < 10; ++c) { lo = fminf(lo, bp[c]); hi = fmaxf(hi, bp[c]); }
  const float step = (hi - lo) / (float)(NL - 3);
  if (t == 0) {
    ws[OFF_PAR]     = (float)(NL - 3) / (hi - lo);          // inv_step
    ws[OFF_PAR + 1] = 1.0f - lo * ((float)(NL - 3) / (hi - lo));  // bias
  }
  if (t < 99) {
    const int s = t / 9, tt = t % 9;      // tt = dr*3 + kc
    const int dr = tt / 3, kc = tt % 3;
    float A = 0.f, Bv = 0.f;
    for (int c = 0; c < 10; ++c) {
      bool act = (w1v[c] > 0.f) ? (rank[c] < s)
               : ((w1v[c] < 0.f) ? (rank[c] >= s) : (b1v[c] > 0.f));
      if (act) { A += w1v[c] * w2[c * 9 + tt]; Bv += b1v[c] * w2[c * 9 + tt]; }
    }
    ws[OFF_TABP + (s * 3 + kc) * 8 + dr * 2]     = A;
    ws[OFF_TABP + (s * 3 + kc) * 8 + dr * 2 + 1] = Bv;
  }
  unsigned short* lut = (unsigned short*)(ws + OFF_LUT);
  for (int k = t; k < NL; k += 256) {      // cell k left edge x = lo + (k-1)*step
    const float x = lo + (float)(k - 1) * step;
    int s = 0;
#pragma unroll
    for (int c = 0; c < 10; ++c) s += (bp[c] < x) ? 1 : 0;
    lut[k] = (unsigned short)(s * 96);
  }
}

// ---- K1: row sums + col-sum partials; LDS-transpose row reduce ----
__global__ __launch_bounds__(256) void sum_kernel(const float* __restrict__ x,
                                                  float* __restrict__ ws) {
  const int bq = blockIdx.x;         // 2048 blocks: 4 per batch (64 rows each)
  const int b = bq >> 2;
  const int q = bq & 3;
  const int tid = threadIdx.x;
  const int lane = tid & 63;
  const int wv = tid >> 6;
  __shared__ float rowp[64][65];
  __shared__ float csl[4][DD];
  __shared__ float segp[4][64];
  float4 cacc = make_float4(0.f, 0.f, 0.f, 0.f);
  const float4* px = (const float4*)(x + ((size_t)b << 16) + ((size_t)(q * 64 + wv * 16) << 8));
#pragma unroll
  for (int r = 0; r < 16; ++r) {
    float4 val = px[r * 64 + lane];
    cacc.x += val.x; cacc.y += val.y; cacc.z += val.z; cacc.w += val.w;
    rowp[wv * 16 + r][lane] = (val.x + val.y) + (val.z + val.w);
  }
  ((float4*)csl[wv])[lane] = cacc;
  __syncthreads();
  {
    const int row = tid & 63, seg = tid >> 6;
    const float* rp = rowp[row] + seg * 16;
    float s = 0.f;
#pragma unroll
    for (int k = 0; k < 16; ++k) s += rp[k];
    segp[seg][row] = s;
  }
  __syncthreads();
  if (tid < 64)
    ws[OFF_RS + b * DD + q * 64 + tid] =
        (segp[0][tid] + segp[1][tid]) + (segp[2][tid] + segp[3][tid]);
  ws[OFF_CSP + bq * DD + tid] =
      (csl[0][tid] + csl[1][tid]) + (csl[2][tid] + csl[3][tid]);
  if (bq == 0 && tid < 4) ws[OFF_HFC + tid] = 0.f;
}

// ---- K2: one block/image; LUT interval lookup; delta accumulation vs yb ----
__global__ __launch_bounds__(1024, 8) void conv_kernel(const float* __restrict__ b2p,
                                                       const float* __restrict__ fc1w,
                                                       float* __restrict__ ws) {
  const int b = blockIdx.x;          // 512 blocks
  const int tid = threadIdx.x;
  const int w = tid >> 6;            // wave 0..15
  const int lane = tid & 63;
  const int q = w >> 2;              // row segment
  const int wb = (w - q) & 3;        // column band (anti-diagonal: balances SIMDs)
  const int seg = q;
  const int j = wb * 64 + lane;
  const int jmin = wb * 64;
  const int r0 = seg * 64, r1 = r0 + 64;

  __shared__ __align__(16) float tabP[264];
  __shared__ float rs_s[DD];
  __shared__ float cs_s[DD];
  __shared__ __align__(16) float wkA[DD][4];   // AoS: 1 b128 per row
  __shared__ unsigned short lut_s[NL];
  __shared__ float segsum_s[4][4];
  __shared__ float red_s[64];

  // ---- preamble ----
  ((unsigned int*)lut_s)[tid] = ((const unsigned int*)(ws + OFF_LUT))[tid];  // all 1024
  if (tid < 256) {
    rs_s[tid] = ws[OFF_RS + b * DD + tid];
  } else if (tid < 512) {
    const int t = tid - 256;
    const float* csp = ws + OFF_CSP + (b * 4) * DD + t;
    cs_s[t] = (csp[0] + csp[DD]) + (csp[2 * DD] + csp[3 * DD]);
  } else if (tid < 768) {
    const int r = tid - 512;
#pragma unroll
    for (int k = 0; k < 4; ++k) wkA[r][k] = fc1w[k * (BB * DD) + b * DD + r];
  } else {
    const int u = tid - 768;
    if (u < 256) tabP[u] = ws[OFF_TABP + u];
  }
  if (tid < 8) tabP[256 + tid] = ws[OFF_TABP + 256 + tid];
  __syncthreads();
  if (tid < 16) {                    // per-segment wk sums for closed-form trivial rows
    const int ss = tid >> 2, k = tid & 3;
    float s = 0.f;
#pragma unroll
    for (int r = 0; r < 64; ++r) s += wkA[ss * 64 + r][k];
    segsum_s[ss][k] = s;
  }
  __syncthreads();

  const float inv_step = ws[OFF_PAR];
  const float bias = ws[OFF_PAR + 1];
  const float b2v = b2p[0];
  const float yb = fmaxf(b2v, 0.f);

  float csr[3], vf[3];
  csr[0] = (j >= 1) ? cs_s[j - 1] : 0.f;
  csr[1] = cs_s[j];
  csr[2] = (j < DD - 1) ? cs_s[j + 1] : 0.f;
  vf[0] = (j >= 1) ? 1.f : 0.f;
  vf[1] = 1.f;
  vf[2] = (j < DD - 1) ? 1.f : 0.f;

  const int nt = min(max(jmin - 2 - r0, 0), 64);   // wave-trivial output rows
  const int rfirst = r0 + nt;
  const int ibeg = (nt > 0) ? rfirst - 1 : ((r0 == 0) ? 0 : r0 - 1);
  const int iend = (r1 == DD) ? DD - 1 : r1;
  const int ffrom = rfirst + 1;                    // first i that finalizes a row

  float P = 0.f, Q = 0.f;
  float vcol = 64.f * yb;                          // closed form: 64 rows of yb
  float acc0 = yb * segsum_s[seg][0];
  float acc1 = yb * segsum_s[seg][1];
  float acc2 = yb * segsum_s[seg][2];
  float acc3 = yb * segsum_s[seg][3];

  if (rfirst < r1) {
    for (int i = ibeg; i <= iend; ++i) {
      const float rsv = rs_s[i];
      float R0 = 0.f, R1 = 0.f, R2 = 0.f;
      if (j - 1 <= i) {
#pragma unroll
        for (int kc = 0; kc < 3; ++kc) {
          const float e = rsv + csr[kc];
          float fx = fmaf(e, inv_step, bias);
          fx = fminf(fmaxf(fx, 0.f), (float)(NL - 1));
          const int off = (int)lut_s[(int)fx];     // s*96 byte offset
          const char* tp = (const char*)tabP + (off + kc * 32);
          const float4 ab01 = *(const float4*)tp;        // A0,B0,A1,B1
          const float2 ab2  = *(const float2*)(tp + 16); // A2,B2
          const float m = ((j - 1 + kc) <= i) ? vf[kc] : 0.f;
          R0 = fmaf(m, fmaf(ab01.x, e, ab01.y), R0);
          R1 = fmaf(m, fmaf(ab01.z, e, ab01.w), R1);
          R2 = fmaf(m, fmaf(ab2.x, e, ab2.y), R2);
        }
      }
      if (i >= ffrom) {              // finalize output row i-1 (wave-uniform branch)
        const float yd = fmaxf(P + R2 + b2v, 0.f) - yb;
        vcol += yd;
        const float4 wkv = *(const float4*)wkA[i - 1];
        acc0 = fmaf(yd, wkv.x, acc0);
        acc1 = fmaf(yd, wkv.y, acc1);
        acc2 = fmaf(yd, wkv.z, acc2);
        acc3 = fmaf(yd, wkv.w, acc3);
      }
      P = Q + R1;
      Q = R0;
    }
  }
  if (r1 == DD) {                    // flush output row 255
    const float yd = fmaxf(P + b2v, 0.f) - yb;
    vcol += yd;
    const float4 wkv = *(const float4*)wkA[DD - 1];
    acc0 = fmaf(yd, wkv.x, acc0);
    acc1 = fmaf(yd, wkv.y, acc1);
    acc2 = fmaf(yd, wkv.z, acc2);
    acc3 = fmaf(yd, wkv.w, acc3);
  }

  // column-sum term: vcol * Wk[b, j]
  const float4 wkj = *(const float4*)wkA[j];
  acc0 = fmaf(vcol, wkj.x, acc0);
  acc1 = fmaf(vcol, wkj.y, acc1);
  acc2 = fmaf(vcol, wkj.z, acc2);
  acc3 = fmaf(vcol, wkj.w, acc3);

  acc0 = wave_red(acc0); acc1 = wave_red(acc1);
  acc2 = wave_red(acc2); acc3 = wave_red(acc3);
  if (lane == 0) {
    red_s[w * 4 + 0] = acc0; red_s[w * 4 + 1] = acc1;
    red_s[w * 4 + 2] = acc2; red_s[w * 4 + 3] = acc3;
  }
  __syncthreads();
  if (tid < 4) {
    float s = 0.f;
#pragma unroll
    for (int wv = 0; wv < 16; ++wv) s += red_s[wv * 4 + tid];
    atomicAdd(&ws[OFF_HFC + tid], s);
  }
}

// ---- K3: relu(fc1) -> fc2 -> 2 outputs ----
__global__ void fc_kernel(const float* __restrict__ fc1b, const float* __restrict__ fc2w,
                          const float* __restrict__ fc2b, const float* __restrict__ ws,
                          float* __restrict__ out) {
  if (threadIdx.x == 0 && blockIdx.x == 0) {
    float o0 = fc2b[0], o1 = fc2b[1];
#pragma unroll
    for (int k = 0; k < 4; ++k) {
      float h = fmaxf(ws[OFF_HFC + k] + fc1b[k], 0.f);
      o0 += fc2w[k] * h;
      o1 += fc2w[4 + k] * h;
    }
    out[0] = o0; out[1] = o1;
  }
}

extern "C" void kernel_launch(void* const* d_in, const int* in_sizes, int n_in,
                              void* d_out, int out_size, void* d_ws, size_t ws_size,
                              hipStream_t stream) {
  const float* x    = (const float*)d_in[0];
  const float* w1   = (const float*)d_in[1];
  const float* b1   = (const float*)d_in[2];
  const float* w2   = (const float*)d_in[3];
  const float* b2   = (const float*)d_in[4];
  const float* fc1w = (const float*)d_in[5];
  const float* fc1b = (const float*)d_in[6];
  const float* fc2w = (const float*)d_in[7];
  const float* fc2b = (const float*)d_in[8];
  float* out = (float*)d_out;
  float* ws  = (float*)d_ws;

  hipLaunchKernelGGL(ktab_kernel, dim3(1), dim3(256), 0, stream, w1, b1, w2, ws);
  hipLaunchKernelGGL(sum_kernel,  dim3(2048), dim3(256), 0, stream, x, ws);
  hipLaunchKernelGGL(conv_kernel, dim3(512), dim3(1024), 0, stream, b2, fc1w, ws);
  hipLaunchKernelGGL(fc_kernel,   dim3(1), dim3(64), 0, stream, fc1b, fc2w, fc2b, ws, out);
}

// Round 6
// 243.150 us; speedup vs baseline: 1.4814x; 1.0269x over previous
//
#include <hip/hip_runtime.h>

#define DD 256
#define BB 512
#define NL 2048            // e-quantization LUT entries

// workspace layout (float offsets)
#define OFF_RS   0          // 512*256 row sums
#define OFF_CSP  131072     // 2048*256 col-sum partials (4 per batch)
#define OFF_HFC  655360     // 4 fc1 pre-activations
#define OFF_PAR  655368     // inv_step, bias
#define OFF_TABP 655376     // 33 rows * 8 floats: (s*3+kc)*8 -> A0,A1,B0,B1,A2,B2,_,_
#define OFF_LUT  655648     // 2048 u16: quantized e -> s*96 byte offset

typedef float v2f __attribute__((ext_vector_type(2)));

__device__ __forceinline__ v2f mk2(float a, float b) { v2f r; r.x = a; r.y = b; return r; }

__device__ __forceinline__ v2f fma2(v2f a, v2f b, v2f c) {
#if __has_builtin(__builtin_elementwise_fma)
  return __builtin_elementwise_fma(a, b, c);   // -> v_pk_fma_f32
#else
  return mk2(fmaf(a.x, b.x, c.x), fmaf(a.y, b.y, c.y));
#endif
}

__device__ __forceinline__ float wave_red(float v) {
#pragma unroll
  for (int off = 32; off > 0; off >>= 1) v += __shfl_down(v, off, 64);
  return v;
}

// ---- K1: row sums + col-sum partials; block 2048 builds PWL tables + LUT ----
__global__ __launch_bounds__(256) void sum_kernel(const float* __restrict__ x,
                                                  const float* __restrict__ w1,
                                                  const float* __restrict__ b1,
                                                  const float* __restrict__ w2,
                                                  float* __restrict__ ws) {
  const int bq = blockIdx.x;
  const int tid = threadIdx.x;
  if (bq == 2048) {                  // ---- table-builder block ----
    const int t = tid;
    float w1v[10], b1v[10], bp[10];
    int rank[10];
#pragma unroll
    for (int c = 0; c < 10; ++c) { w1v[c] = w1[c]; b1v[c] = b1[c]; bp[c] = -b1v[c] / w1v[c]; }
#pragma unroll
    for (int c = 0; c < 10; ++c) {
      int r = 0;
#pragma unroll
      for (int k = 0; k < 10; ++k)
        r += (bp[k] < bp[c] || (bp[k] == bp[c] && k < c)) ? 1 : 0;
      rank[c] = r;
    }
    float lo = bp[0], hi = bp[0];
#pragma unroll
    for (int c = 1; c < 10; ++c) { lo = fminf(lo, bp[c]); hi = fmaxf(hi, bp[c]); }
    const float step = (hi - lo) / (float)(NL - 3);
    if (t == 0) {
      ws[OFF_PAR]     = (float)(NL - 3) / (hi - lo);
      ws[OFF_PAR + 1] = 1.0f - lo * ((float)(NL - 3) / (hi - lo));
    }
    if (t < 99) {
      const int s = t / 9, tt = t % 9;    // tt = dr*3 + kc
      const int dr = tt / 3, kc = tt % 3;
      float A = 0.f, Bv = 0.f;
      for (int c = 0; c < 10; ++c) {
        bool act = (w1v[c] > 0.f) ? (rank[c] < s)
                 : ((w1v[c] < 0.f) ? (rank[c] >= s) : (b1v[c] > 0.f));
        if (act) { A += w1v[c] * w2[c * 9 + tt]; Bv += b1v[c] * w2[c * 9 + tt]; }
      }
      const int base = (s * 3 + kc) * 8;
      const int posA = (dr == 2) ? 4 : dr;
      const int posB = (dr == 2) ? 5 : (2 + dr);
      ws[OFF_TABP + base + posA] = A;
      ws[OFF_TABP + base + posB] = Bv;
      ws[OFF_TABP + base + 6] = 0.f;
      ws[OFF_TABP + base + 7] = 0.f;
    }
    unsigned short* lut = (unsigned short*)(ws + OFF_LUT);
    for (int k = t; k < NL; k += 256) {   // cell k left edge x = lo + (k-1)*step
      const float xx = lo + (float)(k - 1) * step;
      int s = 0;
#pragma unroll
      for (int c = 0; c < 10; ++c) s += (bp[c] < xx) ? 1 : 0;
      lut[k] = (unsigned short)(s * 96);
    }
    return;
  }
  // ---- streaming sum block ----
  const int b = bq >> 2;
  const int q = bq & 3;
  const int lane = tid & 63;
  const int wv = tid >> 6;
  __shared__ float rowp[64][65];
  __shared__ float csl[4][DD];
  __shared__ float segp[4][64];
  float4 cacc = make_float4(0.f, 0.f, 0.f, 0.f);
  const float4* px = (const float4*)(x + ((size_t)b << 16) + ((size_t)(q * 64 + wv * 16) << 8));
#pragma unroll
  for (int r = 0; r < 16; ++r) {
    float4 val = px[r * 64 + lane];
    cacc.x += val.x; cacc.y += val.y; cacc.z += val.z; cacc.w += val.w;
    rowp[wv * 16 + r][lane] = (val.x + val.y) + (val.z + val.w);
  }
  ((float4*)csl[wv])[lane] = cacc;
  __syncthreads();
  {
    const int row = tid & 63, seg = tid >> 6;
    const float* rp = rowp[row] + seg * 16;
    float s = 0.f;
#pragma unroll
    for (int k = 0; k < 16; ++k) s += rp[k];
    segp[seg][row] = s;
  }
  __syncthreads();
  if (tid < 64)
    ws[OFF_RS + b * DD + q * 64 + tid] =
        (segp[0][tid] + segp[1][tid]) + (segp[2][tid] + segp[3][tid]);
  ws[OFF_CSP + bq * DD + tid] =
      (csl[0][tid] + csl[1][tid]) + (csl[2][tid] + csl[3][tid]);
  if (bq == 0 && tid < 4) ws[OFF_HFC + tid] = 0.f;
}

// ---- K2: one block/image; LUT lookup; packed fp32; interior fast loop ----
__global__ __launch_bounds__(1024, 8) void conv_kernel(const float* __restrict__ b2p,
                                                       const float* __restrict__ fc1w,
                                                       float* __restrict__ ws) {
  const int b = blockIdx.x;          // 512 blocks
  const int tid = threadIdx.x;
  const int w = tid >> 6;            // wave 0..15
  const int lane = tid & 63;
  const int seg = w >> 2;            // row segment
  const int wb = (w - seg) & 3;      // column band (anti-diagonal balance)
  const int j = wb * 64 + lane;
  const int jmin = wb * 64;
  const int r0 = seg * 64, r1 = r0 + 64;

  __shared__ __align__(16) float tabP[264];
  __shared__ float rs_s[DD];
  __shared__ float cs_s[DD];
  __shared__ __align__(16) float wkA[DD][4];
  __shared__ unsigned short lut_s[NL];
  __shared__ float segsum_s[4][4];
  __shared__ float red_s[64];

  // ---- preamble ----
  ((unsigned int*)lut_s)[tid] = ((const unsigned int*)(ws + OFF_LUT))[tid];
  if (tid < 256) {
    rs_s[tid] = ws[OFF_RS + b * DD + tid];
  } else if (tid < 512) {
    const int t = tid - 256;
    const float* csp = ws + OFF_CSP + (b * 4) * DD + t;
    cs_s[t] = (csp[0] + csp[DD]) + (csp[2 * DD] + csp[3 * DD]);
  } else if (tid < 768) {
    const int r = tid - 512;
#pragma unroll
    for (int k = 0; k < 4; ++k) wkA[r][k] = fc1w[k * (BB * DD) + b * DD + r];
  } else {
    const int u = tid - 768;
    if (u < 256) tabP[u] = ws[OFF_TABP + u];
  }
  if (tid < 8) tabP[256 + tid] = ws[OFF_TABP + 256 + tid];
  __syncthreads();
  if (tid < 16) {
    const int ss = tid >> 2, k = tid & 3;
    float s = 0.f;
#pragma unroll
    for (int r = 0; r < 64; ++r) s += wkA[ss * 64 + r][k];
    segsum_s[ss][k] = s;
  }
  __syncthreads();

  const float inv_step = ws[OFF_PAR];
  const float bias = ws[OFF_PAR + 1];
  const float b2v = b2p[0];
  const float yb = fmaxf(b2v, 0.f);
  const float fxmax = (float)(NL - 1);

  float csr[3], vf[3];
  csr[0] = (j >= 1) ? cs_s[j - 1] : 0.f;
  csr[1] = cs_s[j];
  csr[2] = (j < DD - 1) ? cs_s[j + 1] : 0.f;
  vf[0] = (j >= 1) ? 1.f : 0.f;
  vf[1] = 1.f;
  vf[2] = (j < DD - 1) ? 1.f : 0.f;
  v2f vf2[3];
#pragma unroll
  for (int kc = 0; kc < 3; ++kc) vf2[kc] = mk2(vf[kc], vf[kc]);

  const int nt = min(max(jmin - 2 - r0, 0), 64);   // wave-trivial output rows
  const int rfirst = r0 + nt;
  const int iend = (r1 == DD) ? DD - 1 : r1;

  float P = 0.f, Q = 0.f;
  float vcol = 64.f * yb;                          // closed form yb contribution
  v2f a01 = mk2(yb * segsum_s[seg][0], yb * segsum_s[seg][1]);
  v2f a23 = mk2(yb * segsum_s[seg][2], yb * segsum_s[seg][3]);

#define TAP_CORE(KC, E, M2, MS)                                              \
  {                                                                          \
    float fx = fmaf((E), inv_step, bias);                                    \
    fx = fminf(fmaxf(fx, 0.f), fxmax);                                       \
    const int off = (int)lut_s[(int)fx];                                     \
    const char* tp = (const char*)tabP + (off + (KC) * 32);                  \
    const float4 ab = *(const float4*)tp;         /* A0,A1,B0,B1 */          \
    const float2 ab2 = *(const float2*)(tp + 16); /* A2,B2 */                \
    v2f tv = fma2(mk2(ab.x, ab.y), mk2((E), (E)), mk2(ab.z, ab.w));          \
    R01 = fma2((M2), tv, R01);                                               \
    R2 = fmaf((MS), fmaf(ab2.x, (E), ab2.y), R2);                            \
  }

  if (rfirst < r1) {
    if (seg > wb) {
      // ---- 2 guarded warmup iters (no finalize): i = r0-1, r0 ----
      for (int i = r0 - 1; i <= r0; ++i) {
        const float rsv = rs_s[i];
        v2f R01 = mk2(0.f, 0.f); float R2 = 0.f;
#pragma unroll
        for (int kc = 0; kc < 3; ++kc) {
          const float e = rsv + csr[kc];
          const float m = ((j - 1 + kc) <= i) ? vf[kc] : 0.f;
          TAP_CORE(kc, e, mk2(m, m), m)
        }
        P = Q + R01.y; Q = R01.x;
      }
      // ---- interior loop: all lanes in-tril, finalize every iter ----
      for (int i = r0 + 1; i <= iend; ++i) {
        const float rsv = rs_s[i];
        v2f R01 = mk2(0.f, 0.f); float R2 = 0.f;
#pragma unroll
        for (int kc = 0; kc < 3; ++kc) {
          const float e = rsv + csr[kc];
          TAP_CORE(kc, e, vf2[kc], vf[kc])
        }
        const float yd = fmaxf(P + R2 + b2v, 0.f) - yb;
        vcol += yd;
        const float4 wkv = *(const float4*)wkA[i - 1];
        a01 = fma2(mk2(yd, yd), mk2(wkv.x, wkv.y), a01);
        a23 = fma2(mk2(yd, yd), mk2(wkv.z, wkv.w), a23);
        P = Q + R01.y; Q = R01.x;
      }
    } else {
      // ---- guarded loop (diagonal / near-trivial waves) ----
      const int ibeg = (nt > 0) ? rfirst - 1 : ((r0 == 0) ? 0 : r0 - 1);
      const int ffrom = rfirst + 1;
      for (int i = ibeg; i <= iend; ++i) {
        const float rsv = rs_s[i];
        v2f R01 = mk2(0.f, 0.f); float R2 = 0.f;
        if (j - 1 <= i) {
#pragma unroll
          for (int kc = 0; kc < 3; ++kc) {
            const float e = rsv + csr[kc];
            const float m = ((j - 1 + kc) <= i) ? vf[kc] : 0.f;
            TAP_CORE(kc, e, mk2(m, m), m)
          }
        }
        if (i >= ffrom) {
          const float yd = fmaxf(P + R2 + b2v, 0.f) - yb;
          vcol += yd;
          const float4 wkv = *(const float4*)wkA[i - 1];
          a01 = fma2(mk2(yd, yd), mk2(wkv.x, wkv.y), a01);
          a23 = fma2(mk2(yd, yd), mk2(wkv.z, wkv.w), a23);
        }
        P = Q + R01.y; Q = R01.x;
      }
    }
  }
  if (r1 == DD) {                    // flush output row 255
    const float yd = fmaxf(P + b2v, 0.f) - yb;
    vcol += yd;
    const float4 wkv = *(const float4*)wkA[DD - 1];
    a01 = fma2(mk2(yd, yd), mk2(wkv.x, wkv.y), a01);
    a23 = fma2(mk2(yd, yd), mk2(wkv.z, wkv.w), a23);
  }

  // column-sum term: vcol * Wk[b, j]
  const float4 wkj = *(const float4*)wkA[j];
  a01 = fma2(mk2(vcol, vcol), mk2(wkj.x, wkj.y), a01);
  a23 = fma2(mk2(vcol, vcol), mk2(wkj.z, wkj.w), a23);

  float acc0 = wave_red(a01.x), acc1 = wave_red(a01.y);
  float acc2 = wave_red(a23.x), acc3 = wave_red(a23.y);
  if (lane == 0) {
    red_s[w * 4 + 0] = acc0; red_s[w * 4 + 1] = acc1;
    red_s[w * 4 + 2] = acc2; red_s[w * 4 + 3] = acc3;
  }
  __syncthreads();
  if (tid < 4) {
    float s = 0.f;
#pragma unroll
    for (int wv = 0; wv < 16; ++wv) s += red_s[wv * 4 + tid];
    atomicAdd(&ws[OFF_HFC + tid], s);
  }
#undef TAP_CORE
}

// ---- K3: relu(fc1) -> fc2 -> 2 outputs ----
__global__ void fc_kernel(const float* __restrict__ fc1b, const float* __restrict__ fc2w,
                          const float* __restrict__ fc2b, const float* __restrict__ ws,
                          float* __restrict__ out) {
  if (threadIdx.x == 0 && blockIdx.x == 0) {
    float o0 = fc2b[0], o1 = fc2b[1];
#pragma unroll
    for (int k = 0; k < 4; ++k) {
      float h = fmaxf(ws[OFF_HFC + k] + fc1b[k], 0.f);
      o0 += fc2w[k] * h;
      o1 += fc2w[4 + k] * h;
    }
    out[0] = o0; out[1] = o1;
  }
}

extern "C" void kernel_launch(void* const* d_in, const int* in_sizes, int n_in,
                              void* d_out, int out_size, void* d_ws, size_t ws_size,
                              hipStream_t stream) {
  const float* x    = (const float*)d_in[0];
  const float* w1   = (const float*)d_in[1];
  const float* b1   = (const float*)d_in[2];
  const float* w2   = (const float*)d_in[3];
  const float* b2   = (const float*)d_in[4];
  const float* fc1w = (const float*)d_in[5];
  const float* fc1b = (const float*)d_in[6];
  const float* fc2w = (const float*)d_in[7];
  const float* fc2b = (const float*)d_in[8];
  float* out = (float*)d_out;
  float* ws  = (float*)d_ws;

  hipLaunchKernelGGL(sum_kernel,  dim3(2049), dim3(256), 0, stream, x, w1, b1, w2, ws);
  hipLaunchKernelGGL(conv_kernel, dim3(512), dim3(1024), 0, stream, b2, fc1w, ws);
  hipLaunchKernelGGL(fc_kernel,   dim3(1), dim3(64), 0, stream, fc1b, fc2w, fc2b, ws, out);
}